// Round 6
// baseline (18820.140 us; speedup 1.0000x reference)
//
#include <hip/hip_runtime.h>
#include <math.h>

#define ROWS_ 51200  // B*N = 64*800

typedef _Float16 f16_t;
typedef _Float16 half8 __attribute__((ext_vector_type(8)));
typedef float f32x4 __attribute__((ext_vector_type(4)));

struct Params {
  const float* x_seq; const float* t_x; const float* t_y; const float* G;
  const float* Wraw[8]; const float* bia[8];   // idx = dec*4 + layer*2 + cand
  const float* mW1; const float* mb1; const float* mW2; const float* mb2;
  const float* mem; const float* Wa; const float* fc; const float* projW; const float* projb;
  float* dout;
  float* A1; float* U; float* h0; float* h1;
  float* txe; float* tye; float* hidb; float* partial;
  f16_t* Zh;                      // activations, f16. ldz = 208 (L0) / 384 (L1)
  f16_t* A1h; f16_t* A2h; f16_t* Apk1; f16_t* Apk2;
  f16_t* wh[8]; f16_t* wl[8];
};

__device__ __forceinline__ float sigm(float x) { return 1.0f / (1.0f + expf(-x)); }

// ================= prologue =================

__global__ void __launch_bounds__(256) k_p0(Params p) {
  int nt = gridDim.x * blockDim.x, id = blockIdx.x * blockDim.x + threadIdx.x;
  float4 z = {0.f, 0.f, 0.f, 0.f};
  for (int i = id; i < ROWS_ * 16; i += nt) { ((float4*)p.h0)[i] = z; ((float4*)p.h1)[i] = z; }
  for (int i = id; i < 640000; i += nt) {
    int m = i / 800, n = i - m * 800;
    float v = p.G[n * 800 + m];
    p.A1[i] = v;
    p.A1h[i] = (f16_t)v;
  }
  for (int w = 0; w < 8; ++w) {
    int layer = (w >> 1) & 1, cand = w & 1;
    int P = layer ? 128 : 68, NC = cand ? 64 : 128, Kp = layer ? 384 : 224;
    const float* W = p.Wraw[w];
    f16_t* Wth = p.wh[w];
    f16_t* Wtl = p.wl[w];
    for (int idx = id; idx < Kp * NC; idx += nt) {
      int i = idx / NC, c = idx - i * NC;
      float v = 0.f;
      if (i < 3 * P) {
        int k = i / P, pp = i - k * P;
        if (k == 0)
          v = W[(size_t)pp * NC + c] + 0.05f * (W[(size_t)(P + pp) * NC + c] + W[(size_t)(2 * P + pp) * NC + c]);
        else
          v = 0.95f * W[(size_t)i * NC + c];
      }
      f16_t h = (f16_t)v;
      Wth[(size_t)c * Kp + i] = h;
      Wtl[(size_t)c * Kp + i] = (f16_t)((v - (float)h) * 2048.0f);
    }
  }
  for (int idx = id; idx < 15360; idx += nt) {
    int half = idx / 7680, rem = idx - half * 7680;
    int r = rem / 10, j = rem - r * 10;
    const float* tin = half ? p.t_y : p.t_x;
    float a = p.mb1[j];
    for (int k = 0; k < 60; ++k) a += tin[(size_t)r * 60 + k] * p.mW1[k * 10 + j];
    p.hidb[idx] = a;
  }
}

// T2 = 2*A1@A1 - I (f16 out) + mlp_out
__global__ void __launch_bounds__(256) k_p1(Params p) {
  __shared__ float As[16 * 68];
  __shared__ float Bs[16 * 68];
  int tid = threadIdx.x, tx = tid & 15, ty = tid >> 4;
  const float* A = p.A1;
  for (int tile = blockIdx.x; tile < 169; tile += gridDim.x) {
    int bx = tile % 13, by = tile / 13;
    int rowBase = by * 64, colBase = bx * 64;
    float acc[4][4] = {};
    for (int k0 = 0; k0 < 800; k0 += 16) {
      __syncthreads();
      for (int e = tid; e < 1024; e += 256) {
        int r = e >> 4, c = e & 15;
        int gr = rowBase + r;
        As[c * 68 + r] = (gr < 800) ? A[gr * 800 + k0 + c] : 0.f;
      }
      for (int e = tid; e < 1024; e += 256) {
        int r = e >> 6, c = e & 63;
        int gc = colBase + c;
        Bs[r * 68 + c] = (gc < 800) ? A[(k0 + r) * 800 + gc] : 0.f;
      }
      __syncthreads();
#pragma unroll
      for (int kk = 0; kk < 16; ++kk) {
        float4 a4 = *(const float4*)&As[kk * 68 + ty * 4];
        float4 b4 = *(const float4*)&Bs[kk * 68 + tx * 4];
        float av[4] = {a4.x, a4.y, a4.z, a4.w};
        float bv[4] = {b4.x, b4.y, b4.z, b4.w};
#pragma unroll
        for (int i = 0; i < 4; ++i)
#pragma unroll
          for (int j = 0; j < 4; ++j) acc[i][j] += av[i] * bv[j];
      }
    }
#pragma unroll
    for (int i = 0; i < 4; ++i) {
      int m = rowBase + ty * 4 + i;
      if (m >= 800) continue;
#pragma unroll
      for (int j = 0; j < 4; ++j) {
        int n = colBase + tx * 4 + j;
        if (n < 800) p.A2h[m * 800 + n] = (f16_t)(2.f * acc[i][j] - (m == n ? 1.f : 0.f));
      }
    }
  }
  int nt = gridDim.x * blockDim.x, id = blockIdx.x * blockDim.x + threadIdx.x;
  for (int idx = id; idx < 2 * 768 * 1600; idx += nt) {
    int half = idx / (768 * 1600), rem = idx - half * (768 * 1600);
    int r = rem / 1600, o = rem - r * 1600;
    const float* hid = p.hidb + half * 7680;
    float* emb = half ? p.tye : p.txe;
    float a = p.mb2[o];
#pragma unroll
    for (int k = 0; k < 10; ++k) a += hid[r * 10 + k] * p.mW2[k * 1600 + o];
    emb[rem] = a;
  }
}

// pack A into k-panel layout: Apk[(k>>5)][m][k&31]
__global__ void __launch_bounds__(256) k_p2(Params p) {
  int nt = gridDim.x * blockDim.x, id = blockIdx.x * blockDim.x + threadIdx.x;
  for (int i = id; i < 640000; i += nt) {
    int m = i / 800, k = i - m * 800;
    size_t dst = (size_t)(k >> 5) * 25600 + m * 32 + (k & 31);
    p.Apk1[dst] = p.A1h[i];
    p.Apk2[dst] = p.A2h[i];
  }
}

// scalar source gather for layer0 (cols: 0-1 x, 2-3 emb, 4-67 h0)
__device__ __forceinline__ float zread0(const Params& p, int mode, int t, int b, int n, int c) {
  size_t rn = (size_t)b * 800 + n;
  if (c >= 4) return p.h0[rn * 64 + c - 4];
  if (c < 2) {
    if (mode == 0) return p.x_seq[((size_t)(b * 12 + t) * 800 + n) * 2 + c];
    return (t == 0) ? 0.f : p.dout[((size_t)(b * 12 + (t - 1)) * 800 + n) * 2 + c];
  }
  const float* e = (mode == 0) ? p.txe : p.tye;
  return e[(size_t)(b * 12 + t) * 1600 + n * 2 + (c - 2)];
}

// ================= persistent-Z graph MFMA =================
// block = (b, 32-col tile) x row-half; Z slice in LDS once; A global->reg double-buffered; no k-loop barriers.
template <int LAYER>
__global__ void __launch_bounds__(256, 3) g_graph2(Params p, int mode, int t, int inW, int outOff) {
  const int ldz = LAYER ? 384 : 208;
  const int P = LAYER ? 128 : 68;
  const int Pin = LAYER ? 64 : 4;
  __shared__ f16_t ZS[32 * 808];
  int tid = threadIdx.x;
  int ct = (inW + 31) >> 5;
  int b = blockIdx.x / ct;
  int cti = blockIdx.x - b * ct;
  int colBase = cti * 32;
  f16_t* Zb = p.Zh + (size_t)b * 800 * ldz;

  // ---- Z load: 32 cols x 800 n, once ----
  {
    int c0 = (tid & 7) * 4;
    int n0 = tid >> 3;
    for (int pass = 0; pass < 25; ++pass) {
      int n = pass * 32 + n0;
      f16_t hv[4];
      if (mode == 3) {
        *(uint2*)hv = *(const uint2*)(Zb + (size_t)n * ldz + Pin + colBase + c0);
      } else if (LAYER == 1) {
        int cc = colBase + c0;
        const float* src = (cc < 64) ? (p.h0 + ((size_t)b * 800 + n) * 64 + cc)
                                     : (p.h1 + ((size_t)b * 800 + n) * 64 + cc - 64);
        float4 v = *(const float4*)src;
        hv[0] = (f16_t)v.x; hv[1] = (f16_t)v.y; hv[2] = (f16_t)v.z; hv[3] = (f16_t)v.w;
        if (blockIdx.y == 0) *(uint2*)(Zb + (size_t)n * ldz + cc) = *(uint2*)hv;
      } else {
#pragma unroll
        for (int i = 0; i < 4; ++i) {
          int cc = colBase + c0 + i;
          float v = (cc < 68) ? zread0(p, mode, t, b, n, cc) : 0.f;
          hv[i] = (f16_t)v;
          if (blockIdx.y == 0 && cc < 68) Zb[(size_t)n * ldz + cc] = hv[i];
        }
      }
#pragma unroll
      for (int i = 0; i < 4; ++i) ZS[(c0 + i) * 808 + n] = hv[i];
    }
  }
  __syncthreads();

  int lane = tid & 63, wid = tid >> 6;
  int lrow = lane & 15, lgrp = lane >> 4;
  int ybLo = blockIdx.y ? 4 : 0, ybHi = blockIdx.y ? 7 : 4;
  const f16_t* __restrict__ Apk1 = p.Apk1;
  const f16_t* __restrict__ Apk2 = p.Apk2;

  for (int yb = ybLo; yb < ybHi; ++yb) {
    int r0 = yb * 128 + wid * 32;
    int rA0 = r0 + lrow; if (rA0 > 799) rA0 = 799;
    int rA1 = r0 + 16 + lrow; if (rA1 > 799) rA1 = 799;
    f32x4 acc[2][2][2];
#pragma unroll
    for (int m = 0; m < 2; ++m)
#pragma unroll
      for (int q = 0; q < 2; ++q)
#pragma unroll
        for (int r = 0; r < 2; ++r) acc[m][q][r] = (f32x4){0.f, 0.f, 0.f, 0.f};

    half8 a1A[2], a2A[2], a1B[2], a2B[2];
    auto loadA = [&](int ks, half8* a1, half8* a2) {
      size_t base = (size_t)ks * 25600 + lgrp * 8;
      a1[0] = *(const half8*)(Apk1 + base + (size_t)rA0 * 32);
      a1[1] = *(const half8*)(Apk1 + base + (size_t)rA1 * 32);
      a2[0] = *(const half8*)(Apk2 + base + (size_t)rA0 * 32);
      a2[1] = *(const half8*)(Apk2 + base + (size_t)rA1 * 32);
    };
    auto compute = [&](int ks, half8* a1, half8* a2) {
      half8 fz0 = *(const half8*)(ZS + (size_t)lrow * 808 + ks * 32 + lgrp * 8);
      half8 fz1 = *(const half8*)(ZS + (size_t)(16 + lrow) * 808 + ks * 32 + lgrp * 8);
      acc[0][0][0] = __builtin_amdgcn_mfma_f32_16x16x32_f16(a1[0], fz0, acc[0][0][0], 0, 0, 0);
      acc[0][0][1] = __builtin_amdgcn_mfma_f32_16x16x32_f16(a1[0], fz1, acc[0][0][1], 0, 0, 0);
      acc[0][1][0] = __builtin_amdgcn_mfma_f32_16x16x32_f16(a1[1], fz0, acc[0][1][0], 0, 0, 0);
      acc[0][1][1] = __builtin_amdgcn_mfma_f32_16x16x32_f16(a1[1], fz1, acc[0][1][1], 0, 0, 0);
      acc[1][0][0] = __builtin_amdgcn_mfma_f32_16x16x32_f16(a2[0], fz0, acc[1][0][0], 0, 0, 0);
      acc[1][0][1] = __builtin_amdgcn_mfma_f32_16x16x32_f16(a2[0], fz1, acc[1][0][1], 0, 0, 0);
      acc[1][1][0] = __builtin_amdgcn_mfma_f32_16x16x32_f16(a2[1], fz0, acc[1][1][0], 0, 0, 0);
      acc[1][1][1] = __builtin_amdgcn_mfma_f32_16x16x32_f16(a2[1], fz1, acc[1][1][1], 0, 0, 0);
    };

    loadA(0, a1A, a2A);
    for (int ks = 0; ks < 25; ks += 2) {
      if (ks + 1 < 25) loadA(ks + 1, a1B, a2B);
      compute(ks, a1A, a2A);
      if (ks + 2 < 25) loadA(ks + 2, a1A, a2A);
      if (ks + 1 < 25) compute(ks + 1, a1B, a2B);
    }

    f16_t* o1 = Zb + P + outOff;
    f16_t* o2 = Zb + 2 * P + outOff;
#pragma unroll
    for (int pos = 0; pos < 2; ++pos)
#pragma unroll
      for (int cp = 0; cp < 2; ++cp) {
        int col = colBase + cp * 16 + lrow;
        if (col < inW) {
#pragma unroll
          for (int j = 0; j < 4; ++j) {
            int r = r0 + pos * 16 + lgrp * 4 + j;
            if (r < 800) {
              o1[(size_t)r * ldz + col] = (f16_t)acc[0][pos][cp][j];
              o2[(size_t)r * ldz + col] = (f16_t)acc[1][pos][cp][j];
            }
          }
        }
      }
  }
}

// ================= gate proj: 64 rows x 128 cols, f16 Z, W hi/lo =================
template <int LAYER>
__global__ void __launch_bounds__(256, 4) g_gate2(Params p, int dec) {
  const int ldz = LAYER ? 384 : 208;
  const int Kp = LAYER ? 384 : 224;
  const int NK = Kp / 32;
  const int Pin = LAYER ? 64 : 4;
  int widx = dec * 4 + LAYER * 2;
  const f16_t* __restrict__ Wth = p.wh[widx];
  const f16_t* __restrict__ Wtl = p.wl[widx];
  const float* bias = p.bia[widx];
  const float* h = LAYER ? p.h1 : p.h0;
  __shared__ __align__(16) f16_t ZhS[64 * 40];
  __shared__ __align__(16) f16_t WhS[128 * 40];
  __shared__ __align__(16) f16_t WlS[128 * 40];
  int tid = threadIdx.x;
  int lane = tid & 63, wid = tid >> 6;
  int lrow = lane & 15, lgrp = lane >> 4;
  int zrow = tid >> 2, zq = tid & 3;
  int wcol = tid >> 1, whalf = tid & 1;
  int rowBase = blockIdx.x * 64;

  uint4 rz, rwh[2], rwl[2];
  auto prefetch = [&](int ks) {
    int k0 = ks * 32;
    rz = *(const uint4*)(p.Zh + (size_t)(rowBase + zrow) * ldz + k0 + zq * 8);
    size_t g = (size_t)wcol * Kp + k0 + whalf * 16;
    rwh[0] = *(const uint4*)(Wth + g);
    rwh[1] = *(const uint4*)(Wth + g + 8);
    rwl[0] = *(const uint4*)(Wtl + g);
    rwl[1] = *(const uint4*)(Wtl + g + 8);
  };

  f32x4 aM[4][2], aC[4][2];
#pragma unroll
  for (int mt = 0; mt < 4; ++mt)
#pragma unroll
    for (int q = 0; q < 2; ++q) {
      aM[mt][q] = (f32x4){0.f, 0.f, 0.f, 0.f};
      aC[mt][q] = (f32x4){0.f, 0.f, 0.f, 0.f};
    }

  prefetch(0);
  for (int ks = 0; ks < NK; ++ks) {
    if (ks) __syncthreads();
    *(uint4*)(ZhS + zrow * 40 + zq * 8) = rz;
    int sw = wcol * 40 + whalf * 16;
    *(uint4*)(WhS + sw) = rwh[0];
    *(uint4*)(WhS + sw + 8) = rwh[1];
    *(uint4*)(WlS + sw) = rwl[0];
    *(uint4*)(WlS + sw + 8) = rwl[1];
    if (ks + 1 < NK) prefetch(ks + 1);
    __syncthreads();
    half8 fwh[2], fwl[2];
#pragma unroll
    for (int q = 0; q < 2; ++q) {
      int c = wid * 32 + q * 16 + lrow;
      fwh[q] = *(const half8*)(WhS + c * 40 + lgrp * 8);
      fwl[q] = *(const half8*)(WlS + c * 40 + lgrp * 8);
    }
#pragma unroll
    for (int mt = 0; mt < 4; ++mt) {
      half8 fzh = *(const half8*)(ZhS + (mt * 16 + lrow) * 40 + lgrp * 8);
#pragma unroll
      for (int q = 0; q < 2; ++q) {
        aM[mt][q] = __builtin_amdgcn_mfma_f32_16x16x32_f16(fzh, fwh[q], aM[mt][q], 0, 0, 0);
        aC[mt][q] = __builtin_amdgcn_mfma_f32_16x16x32_f16(fzh, fwl[q], aC[mt][q], 0, 0, 0);
      }
    }
  }

#pragma unroll
  for (int mt = 0; mt < 4; ++mt)
#pragma unroll
    for (int q = 0; q < 2; ++q) {
      int col = wid * 32 + q * 16 + lrow;
#pragma unroll
      for (int j = 0; j < 4; ++j) {
        int row = rowBase + mt * 16 + lgrp * 4 + j;
        float v = aM[mt][q][j] + aC[mt][q][j] * (1.0f / 2048.0f) + bias[col];
        if (col < 64) {
          p.U[(size_t)row * 64 + col] = sigm(v);
        } else {
          int jj = col - 64;
          p.Zh[(size_t)row * ldz + Pin + jj] = (f16_t)(sigm(v) * h[(size_t)row * 64 + jj]);
        }
      }
    }
}

// ================= candidate proj: 128 rows x 64 cols, f16 Z, W hi/lo =================
template <int LAYER>
__global__ void __launch_bounds__(256, 4) g_cand2(Params p, int dec) {
  const int ldz = LAYER ? 384 : 208;
  const int Kp = LAYER ? 384 : 224;
  const int NK = Kp / 32;
  int widx = dec * 4 + LAYER * 2 + 1;
  const f16_t* __restrict__ Wth = p.wh[widx];
  const f16_t* __restrict__ Wtl = p.wl[widx];
  const float* bias = p.bia[widx];
  float* h = LAYER ? p.h1 : p.h0;
  __shared__ __align__(16) f16_t ZhS[128 * 40];
  __shared__ __align__(16) f16_t WhS[64 * 40];
  __shared__ __align__(16) f16_t WlS[64 * 40];
  int tid = threadIdx.x;
  int lane = tid & 63, wid = tid >> 6;
  int waveM = wid >> 1, waveN = wid & 1;
  int lrow = lane & 15, lgrp = lane >> 4;
  int zrow = tid >> 1, zhalf = tid & 1;
  int wcol = tid >> 2, wq = tid & 3;
  int rowBase = blockIdx.x * 128;

  uint4 rz[2], rwh, rwl;
  auto prefetch = [&](int ks) {
    int k0 = ks * 32;
    const f16_t* src = p.Zh + (size_t)(rowBase + zrow) * ldz + k0 + zhalf * 16;
    rz[0] = *(const uint4*)src;
    rz[1] = *(const uint4*)(src + 8);
    size_t g = (size_t)wcol * Kp + k0 + wq * 8;
    rwh = *(const uint4*)(Wth + g);
    rwl = *(const uint4*)(Wtl + g);
  };

  f32x4 aM[4][2], aC[4][2];
#pragma unroll
  for (int mt = 0; mt < 4; ++mt)
#pragma unroll
    for (int q = 0; q < 2; ++q) {
      aM[mt][q] = (f32x4){0.f, 0.f, 0.f, 0.f};
      aC[mt][q] = (f32x4){0.f, 0.f, 0.f, 0.f};
    }

  prefetch(0);
  for (int ks = 0; ks < NK; ++ks) {
    if (ks) __syncthreads();
    int s = zrow * 40 + zhalf * 16;
    *(uint4*)(ZhS + s) = rz[0];
    *(uint4*)(ZhS + s + 8) = rz[1];
    int sw = wcol * 40 + wq * 8;
    *(uint4*)(WhS + sw) = rwh;
    *(uint4*)(WlS + sw) = rwl;
    if (ks + 1 < NK) prefetch(ks + 1);
    __syncthreads();
    half8 fwh[2], fwl[2];
#pragma unroll
    for (int q = 0; q < 2; ++q) {
      int c = waveN * 32 + q * 16 + lrow;
      fwh[q] = *(const half8*)(WhS + c * 40 + lgrp * 8);
      fwl[q] = *(const half8*)(WlS + c * 40 + lgrp * 8);
    }
#pragma unroll
    for (int mt = 0; mt < 4; ++mt) {
      half8 fzh = *(const half8*)(ZhS + (waveM * 64 + mt * 16 + lrow) * 40 + lgrp * 8);
#pragma unroll
      for (int q = 0; q < 2; ++q) {
        aM[mt][q] = __builtin_amdgcn_mfma_f32_16x16x32_f16(fzh, fwh[q], aM[mt][q], 0, 0, 0);
        aC[mt][q] = __builtin_amdgcn_mfma_f32_16x16x32_f16(fzh, fwl[q], aC[mt][q], 0, 0, 0);
      }
    }
  }

#pragma unroll
  for (int mt = 0; mt < 4; ++mt)
#pragma unroll
    for (int q = 0; q < 2; ++q) {
      int col = waveN * 32 + q * 16 + lrow;
#pragma unroll
      for (int j = 0; j < 4; ++j) {
        int row = rowBase + waveM * 64 + mt * 16 + lgrp * 4 + j;
        float v = aM[mt][q][j] + aC[mt][q][j] * (1.0f / 2048.0f) + bias[col];
        float cc = tanhf(v);
        float u = p.U[(size_t)row * 64 + col];
        float hv = h[(size_t)row * 64 + col];
        h[(size_t)row * 64 + col] = (1.f - u) * hv + u * cc;
      }
    }
}

// ================= memory attention =================

__global__ void __launch_bounds__(256) k_m1(Params p) {
  int gwid = (blockIdx.x * blockDim.x + threadIdx.x) >> 6;
  int nw = (gridDim.x * blockDim.x) >> 6;
  int lane = threadIdx.x & 63;
  for (int tile = gwid; tile < 1024; tile += nw) {
    int cx = tile & 15, b = tile >> 4;
    float acc[8] = {};
    const float* hrow = p.h1 + (size_t)b * 51200 + cx * 3200;
    const float* wbase = p.Wa + (size_t)cx * 3200 * 8;
    for (int i = lane; i < 3200; i += 64) {
      float hv = hrow[i];
      const float* wr = wbase + (size_t)i * 8;
#pragma unroll
      for (int j = 0; j < 8; ++j) acc[j] += hv * wr[j];
    }
#pragma unroll
    for (int s = 1; s < 64; s <<= 1) {
#pragma unroll
      for (int j = 0; j < 8; ++j) acc[j] += __shfl_xor(acc[j], s);
    }
    if (lane == 0) {
#pragma unroll
      for (int j = 0; j < 8; ++j) p.partial[((size_t)b * 16 + cx) * 8 + j] = acc[j];
    }
  }
}

__global__ void __launch_bounds__(256) k_m2(Params p, int t) {
  __shared__ float attv[512];
  int tid = threadIdx.x;
  if (tid < 64) {
    int b = tid;
    float q[8] = {};
    for (int cx = 0; cx < 16; ++cx)
#pragma unroll
      for (int j = 0; j < 8; ++j) q[j] += p.partial[((size_t)b * 16 + cx) * 8 + j];
    float sco[4], mx = -1e30f;
#pragma unroll
    for (int m = 0; m < 4; ++m) {
      float s = 0.f;
#pragma unroll
      for (int d = 0; d < 8; ++d) s += q[d] * p.mem[m * 8 + d];
      sco[m] = s;
      mx = fmaxf(mx, s);
    }
    float se = 0.f;
#pragma unroll
    for (int m = 0; m < 4; ++m) { sco[m] = expf(sco[m] - mx); se += sco[m]; }
#pragma unroll
    for (int d = 0; d < 8; ++d) {
      float av = 0.f;
#pragma unroll
      for (int m = 0; m < 4; ++m) av += (sco[m] / se) * p.mem[m * 8 + d];
      attv[b * 8 + d] = av;
    }
  }
  __syncthreads();
  int nt = gridDim.x * blockDim.x, id = blockIdx.x * blockDim.x + tid;
  for (int row = id; row < ROWS_; row += nt) {
    int b = row / 800, n = row - b * 800;
    const float* av = attv + b * 8;
    float attm[8];
#pragma unroll
    for (int d = 0; d < 8; ++d) {
      float s = 0.f;
#pragma unroll
      for (int m = 0; m < 8; ++m) s += av[m] * p.fc[(size_t)m * 6400 + n * 8 + d];
      attm[d] = s;
    }
    float o0 = p.projb[0], o1 = p.projb[1];
#pragma unroll
    for (int j4 = 0; j4 < 16; ++j4) {
      float4 h4 = *(const float4*)(p.h1 + (size_t)row * 64 + j4 * 4);
      float hv[4] = {h4.x, h4.y, h4.z, h4.w};
#pragma unroll
      for (int i = 0; i < 4; ++i) {
        o0 += hv[i] * p.projW[(j4 * 4 + i) * 2 + 0];
        o1 += hv[i] * p.projW[(j4 * 4 + i) * 2 + 1];
      }
    }
#pragma unroll
    for (int d = 0; d < 8; ++d) {
      o0 += attm[d] * p.projW[(64 + d) * 2 + 0];
      o1 += attm[d] * p.projW[(64 + d) * 2 + 1];
    }
    size_t base = ((size_t)(b * 12 + t) * 800 + n) * 2;
    p.dout[base + 0] = fmaxf(o0, 0.f);
    p.dout[base + 1] = fmaxf(o1, 0.f);
  }
}

// ================= host =================

extern "C" void kernel_launch(void* const* d_in, const int* in_sizes, int n_in,
                              void* d_out, int out_size, void* d_ws, size_t ws_size,
                              hipStream_t stream) {
  Params P;
  P.x_seq = (const float*)d_in[0];
  P.t_x = (const float*)d_in[1];
  P.t_y = (const float*)d_in[2];
  P.G = (const float*)d_in[3];
  P.Wraw[0] = (const float*)d_in[4];  P.bia[0] = (const float*)d_in[5];
  P.Wraw[1] = (const float*)d_in[6];  P.bia[1] = (const float*)d_in[7];
  P.Wraw[2] = (const float*)d_in[8];  P.bia[2] = (const float*)d_in[9];
  P.Wraw[3] = (const float*)d_in[10]; P.bia[3] = (const float*)d_in[11];
  P.Wraw[4] = (const float*)d_in[12]; P.bia[4] = (const float*)d_in[13];
  P.Wraw[5] = (const float*)d_in[14]; P.bia[5] = (const float*)d_in[15];
  P.Wraw[6] = (const float*)d_in[16]; P.bia[6] = (const float*)d_in[17];
  P.Wraw[7] = (const float*)d_in[18]; P.bia[7] = (const float*)d_in[19];
  P.mW1 = (const float*)d_in[20];
  P.mb1 = (const float*)d_in[21];
  P.mW2 = (const float*)d_in[22];
  P.mb2 = (const float*)d_in[23];
  P.mem = (const float*)d_in[24];
  P.Wa = (const float*)d_in[25];
  P.fc = (const float*)d_in[26];
  P.projW = (const float*)d_in[27];
  P.projb = (const float*)d_in[28];
  P.dout = (float*)d_out;

  float* ws = (float*)d_ws;
  size_t off = 0;
  auto alloc = [&](size_t nel) { float* q = ws + off; off += nel; return q; };
  P.A1 = alloc(640000);
  P.A1h = (f16_t*)alloc(320000);
  P.A2h = (f16_t*)alloc(320000);
  P.Apk1 = (f16_t*)alloc(320000);
  P.Apk2 = (f16_t*)alloc(320000);
  P.Zh = (f16_t*)alloc((size_t)ROWS_ * 192 + 64);  // 51200*384 f16 + slack
  P.U = alloc((size_t)ROWS_ * 64);
  P.h0 = alloc((size_t)ROWS_ * 64);
  P.h1 = alloc((size_t)ROWS_ * 64);
  P.txe = alloc((size_t)768 * 1600);
  P.tye = alloc((size_t)768 * 1600);
  P.hidb = alloc(15360);
  P.partial = alloc(8192);
  const int kpnc[8] = {224 * 128, 224 * 64, 384 * 128, 384 * 64, 224 * 128, 224 * 64, 384 * 128, 384 * 64};
  for (int w = 0; w < 8; ++w) {
    P.wh[w] = (f16_t*)alloc((kpnc[w] + 1) / 2);
    P.wl[w] = (f16_t*)alloc((kpnc[w] + 1) / 2);
  }

  k_p0<<<512, 256, 0, stream>>>(P);
  k_p1<<<512, 256, 0, stream>>>(P);
  k_p2<<<512, 256, 0, stream>>>(P);

  auto cell0 = [&](int mode, int dec, int t) {
    g_graph2<0><<<dim3(64 * 3, 2), 256, 0, stream>>>(P, mode, t, 68, 0);
    g_gate2<0><<<800, 256, 0, stream>>>(P, dec);
    g_graph2<0><<<dim3(64 * 2, 2), 256, 0, stream>>>(P, 3, t, 64, 4);
    g_cand2<0><<<400, 256, 0, stream>>>(P, dec);
  };
  auto cell1 = [&](int dec, int t) {
    g_graph2<1><<<dim3(64 * 4, 2), 256, 0, stream>>>(P, 2, t, 128, 0);
    g_gate2<1><<<800, 256, 0, stream>>>(P, dec);
    g_graph2<1><<<dim3(64 * 2, 2), 256, 0, stream>>>(P, 3, t, 64, 64);
    g_cand2<1><<<400, 256, 0, stream>>>(P, dec);
  };

  for (int t = 0; t < 12; ++t) {
    cell0(0, 0, t);
    cell1(0, t);
  }
  for (int t = 0; t < 12; ++t) {
    cell0(1, 1, t);
    cell1(1, t);
    k_m1<<<256, 256, 0, stream>>>(P);
    k_m2<<<200, 256, 0, stream>>>(P, t);
  }
}

// Round 8
// 11814.207 us; speedup vs baseline: 1.5930x; 1.5930x over previous
//
#include <hip/hip_runtime.h>
#include <math.h>

typedef _Float16 f16_t;
typedef _Float16 half8 __attribute__((ext_vector_type(8)));
typedef float f32x4 __attribute__((ext_vector_type(4)));

#define LDK 384
#define NMP 1664  // padded m' dim (2*800 -> 13*128)

struct Params {
  const float *x_seq, *t_x, *t_y, *G;
  const float *Wraw[8], *bia[8];  // idx = dec*4 + layer*2 + cand
  const float *mW1, *mb1, *mW2, *mb2, *mem, *Wa, *fc, *projW, *projb;
  float* dout;
  float *U, *h0, *h1, *txe, *tye, *hidb, *partial, *Wat;
  f16_t *Zin, *Zrh, *Xp, *Atp, *T2h;
  f16_t *wh[8], *wl[8];
};

__device__ __forceinline__ float sigm(float x) { return 1.0f / (1.0f + expf(-x)); }

// ================= prologue =================

__global__ void __launch_bounds__(256) k_pre0(Params p) {
  int nt = gridDim.x * blockDim.x, id = blockIdx.x * blockDim.x + threadIdx.x;
  float4 z = {0.f, 0.f, 0.f, 0.f};
  for (int i = id; i < 64 * 64 * 200; i += nt) { ((float4*)p.h0)[i] = z; ((float4*)p.h1)[i] = z; }
  // weights: fold kappa + transpose + split hi/lo -> Wth[c][Kp]
  for (int w = 0; w < 8; ++w) {
    int layer = (w >> 1) & 1, cand = w & 1;
    int P = layer ? 128 : 68, NC = cand ? 64 : 128, Kp = layer ? 384 : 224;
    const float* W = p.Wraw[w];
    f16_t* Wth = p.wh[w];
    f16_t* Wtl = p.wl[w];
    for (int idx = id; idx < Kp * NC; idx += nt) {
      int i = idx / NC, c = idx - i * NC;
      float v = 0.f;
      if (i < 3 * P) {
        int k = i / P, pp = i - k * P;
        if (k == 0)
          v = W[(size_t)pp * NC + c] + 0.05f * (W[(size_t)(P + pp) * NC + c] + W[(size_t)(2 * P + pp) * NC + c]);
        else
          v = 0.95f * W[(size_t)i * NC + c];
      }
      f16_t h = (f16_t)v;
      Wth[(size_t)c * Kp + i] = h;
      Wtl[(size_t)c * Kp + i] = (f16_t)((v - (float)h) * 2048.0f);
    }
  }
  // mlp hidden
  for (int idx = id; idx < 15360; idx += nt) {
    int half = idx / 7680, rem = idx - half * 7680;
    int r = rem / 10, j = rem - r * 10;
    const float* tin = half ? p.t_y : p.t_x;
    float a = p.mb1[j];
    for (int k = 0; k < 60; ++k) a += tin[(size_t)r * 60 + k] * p.mW1[k * 10 + j];
    p.hidb[idx] = a;
  }
  // Wat[(c*800+n)*8+d] = Wa[(n*64+c)*8+d]
  for (int idx = id; idx < 409600; idx += nt) {
    int c = idx / 6400, r2 = idx - c * 6400;
    int n = r2 >> 3, d = r2 & 7;
    p.Wat[idx] = p.Wa[((size_t)n * 64 + c) * 8 + d];
  }
}

// T2h = 2*G@G - I (f16), plus mlp_out
__global__ void __launch_bounds__(256) k_pre1(Params p) {
  __shared__ float As[16 * 68];
  __shared__ float Bs[16 * 68];
  int tid = threadIdx.x, tx = tid & 15, ty = tid >> 4;
  const float* A = p.G;
  for (int tile = blockIdx.x; tile < 169; tile += gridDim.x) {
    int bx = tile % 13, by = tile / 13;
    int rowBase = by * 64, colBase = bx * 64;
    float acc[4][4] = {};
    for (int k0 = 0; k0 < 800; k0 += 16) {
      __syncthreads();
      for (int e = tid; e < 1024; e += 256) {
        int r = e >> 4, c = e & 15;
        int gr = rowBase + r;
        As[c * 68 + r] = (gr < 800) ? A[gr * 800 + k0 + c] : 0.f;
      }
      for (int e = tid; e < 1024; e += 256) {
        int r = e >> 6, c = e & 63;
        int gc = colBase + c;
        Bs[r * 68 + c] = (gc < 800) ? A[(k0 + r) * 800 + gc] : 0.f;
      }
      __syncthreads();
#pragma unroll
      for (int kk = 0; kk < 16; ++kk) {
        float4 a4 = *(const float4*)&As[kk * 68 + ty * 4];
        float4 b4 = *(const float4*)&Bs[kk * 68 + tx * 4];
        float av[4] = {a4.x, a4.y, a4.z, a4.w};
        float bv[4] = {b4.x, b4.y, b4.z, b4.w};
#pragma unroll
        for (int i = 0; i < 4; ++i)
#pragma unroll
          for (int j = 0; j < 4; ++j) acc[i][j] += av[i] * bv[j];
      }
    }
#pragma unroll
    for (int i = 0; i < 4; ++i) {
      int m = rowBase + ty * 4 + i;
      if (m >= 800) continue;
#pragma unroll
      for (int j = 0; j < 4; ++j) {
        int n = colBase + tx * 4 + j;
        if (n < 800) p.T2h[(size_t)m * 800 + n] = (f16_t)(2.f * acc[i][j] - (m == n ? 1.f : 0.f));
      }
    }
  }
  int nt = gridDim.x * blockDim.x, id = blockIdx.x * blockDim.x + threadIdx.x;
  for (int idx = id; idx < 2 * 768 * 1600; idx += nt) {
    int half = idx / (768 * 1600), rem = idx - half * (768 * 1600);
    int r = rem / 1600, o = rem - r * 1600;
    const float* hid = p.hidb + half * 7680;
    float* emb = half ? p.tye : p.txe;
    float a = p.mb2[o];
#pragma unroll
    for (int k = 0; k < 10; ++k) a += hid[r * 10 + k] * p.mW2[k * 1600 + o];
    emb[rem] = a;
  }
}

// Atp[kp][m'][kk] = B[k][m']; B = [Gt1 | Gt2] where Gt1 = G (A1^T), Gt2 = T2h (A2^T)
__global__ void __launch_bounds__(256) k_pre2(Params p) {
  int nt = gridDim.x * blockDim.x, id = blockIdx.x * blockDim.x + threadIdx.x;
  for (int idx = id; idx < 25 * NMP * 32; idx += nt) {
    int kp = idx / (NMP * 32), r = idx - kp * (NMP * 32);
    int mp = r >> 5, kk = r & 31;
    int k = kp * 32 + kk;
    f16_t v;
    if (mp < 800) v = (f16_t)p.G[(size_t)k * 800 + mp];
    else if (mp < 1600) v = p.T2h[(size_t)k * 800 + (mp - 800)];
    else v = (f16_t)0.f;
    p.Atp[idx] = v;
  }
}

// ================= packs (feature-major) =================

// L0 plane0: rows r = b*68+c; write Zin[r][n] and Xp[b*LDK+c][n]
__global__ void __launch_bounds__(256) g_pack0(Params p, int dec, int t) {
  int r = blockIdx.x;
  int b = r / 68, c = r - b * 68;
  const float* hsrc = p.h0 + (size_t)(b * 64 + (c >= 4 ? c - 4 : 0)) * 800;
  f16_t* z1 = p.Zin + (size_t)r * 800;
  f16_t* z2 = p.Xp + ((size_t)b * LDK + c) * 800;
  for (int n = threadIdx.x; n < 800; n += 256) {
    float v;
    if (c >= 4) v = hsrc[n];
    else if (c < 2) {
      if (dec) v = (t == 0) ? 0.f : p.dout[((size_t)(b * 12 + t - 1) * 800 + n) * 2 + c];
      else v = p.x_seq[((size_t)(b * 12 + t) * 800 + n) * 2 + c];
    } else {
      const float* e = dec ? p.tye : p.txe;
      v = e[(size_t)(b * 12 + t) * 1600 + n * 2 + (c - 2)];
    }
    f16_t h = (f16_t)v;
    z1[n] = h;
    z2[n] = h;
  }
}

// L1 plane0: rows r = b*128+c from h0/h1 col-major
__global__ void __launch_bounds__(256) g_pack1(Params p) {
  int r = blockIdx.x;
  int b = r >> 7, c = r & 127;
  const float* hs = (c < 64) ? p.h0 + (size_t)(b * 64 + c) * 800 : p.h1 + (size_t)(b * 64 + c - 64) * 800;
  f16_t* z1 = p.Zin + (size_t)r * 800;
  f16_t* z2 = p.Xp + ((size_t)b * LDK + c) * 800;
  for (int n = threadIdx.x; n < 800; n += 256) {
    f16_t h = (f16_t)hs[n];
    z1[n] = h;
    z2[n] = h;
  }
}

// ================= graph GEMM: D[r][m'] = sum_k Ain[r][k] * B[k][m'] =================
// grid: x = m'-tile (13), y = row-tile (M/128). Block 128x128, 4 waves 2x2.
template <int PM>
__global__ void __launch_bounds__(256, 2) g_gconv(Params p, const f16_t* __restrict__ Ain, int P, int cOff) {
  __shared__ f16_t AS[128 * 40];
  __shared__ f16_t BS[128 * 40];
  int tid = threadIdx.x, lane = tid & 63, wid = tid >> 6;
  int waveM = wid >> 1, waveN = wid & 1;
  int lrow = lane & 15, lgrp = lane >> 4;
  int mBase = blockIdx.x * 128;
  int rBase = blockIdx.y * 128;
  int srow = tid >> 1, shalf = tid & 1;
  const f16_t* Asrc = Ain + (size_t)(rBase + srow) * 800 + shalf * 16;
  const f16_t* Bsrc = p.Atp + (size_t)(mBase + srow) * 32 + shalf * 16;

  uint4 rA[2], rB[2];
  auto pf = [&](int ks) {
    const f16_t* a = Asrc + ks * 32;
    rA[0] = *(const uint4*)a;
    rA[1] = *(const uint4*)(a + 8);
    const f16_t* bq = Bsrc + (size_t)ks * (NMP * 32);
    rB[0] = *(const uint4*)bq;
    rB[1] = *(const uint4*)(bq + 8);
  };

  f32x4 acc[4][4];
#pragma unroll
  for (int i = 0; i < 4; ++i)
#pragma unroll
    for (int j = 0; j < 4; ++j) acc[i][j] = (f32x4){0.f, 0.f, 0.f, 0.f};

  pf(0);
  for (int ks = 0; ks < 25; ++ks) {
    if (ks) __syncthreads();
    int s = srow * 40 + shalf * 16;
    *(uint4*)(AS + s) = rA[0];
    *(uint4*)(AS + s + 8) = rA[1];
    *(uint4*)(BS + s) = rB[0];
    *(uint4*)(BS + s + 8) = rB[1];
    if (ks + 1 < 25) pf(ks + 1);
    __syncthreads();
    half8 fa[4], fb[4];
#pragma unroll
    for (int mt = 0; mt < 4; ++mt) fa[mt] = *(const half8*)(AS + (waveM * 64 + mt * 16 + lrow) * 40 + lgrp * 8);
#pragma unroll
    for (int nt = 0; nt < 4; ++nt) fb[nt] = *(const half8*)(BS + (waveN * 64 + nt * 16 + lrow) * 40 + lgrp * 8);
#pragma unroll
    for (int mt = 0; mt < 4; ++mt)
#pragma unroll
      for (int nt = 0; nt < 4; ++nt) acc[mt][nt] = __builtin_amdgcn_mfma_f32_16x16x32_f16(fa[mt], fb[nt], acc[mt][nt], 0, 0, 0);
  }

#pragma unroll
  for (int mt = 0; mt < 4; ++mt)
#pragma unroll
    for (int nt = 0; nt < 4; ++nt) {
      int mp = mBase + waveN * 64 + nt * 16 + lrow;
      if (mp >= 1600) continue;
      int pl2 = (mp >= 800);
      int m = mp - (pl2 ? 800 : 0);
      int pbase = (pl2 ? 2 : 1) * P + cOff;
#pragma unroll
      for (int j = 0; j < 4; ++j) {
        int r = rBase + waveM * 64 + mt * 16 + lgrp * 4 + j;
        int b = r / PM, c = r - b * PM;
        p.Xp[((size_t)b * LDK + pbase + c) * 800 + m] = (f16_t)acc[mt][nt][j];
      }
    }
}

// ================= proj (transposed): D[c_out][n] = sum_k Wfold[k][c_out] * X[b][k][n] =================
// grid: x = n-tile (13 of 64), y = b. Block BM=NC x BN=64, 4 waves along M.
// MODE 0 epilogue: U = sigm(u); rh = sigm(r)*h -> Zrh (gconv#2 input) AND Xp plane0 h-slot (cand proj input).
template <int NC, int MODE>
__global__ void __launch_bounds__(256, 3) g_proj(Params p, int widx, int K3, int Pin, float* hcur) {
  const int NKT = (K3 + 31) >> 5;
  const int Kp = NKT * 32;
  const int MW = NC / 4;       // rows per wave
  const int NMF = MW / 16;     // m-frags per wave
  const int SL = (NC * 4) / 256;  // W stage slots per thread
  __shared__ f16_t WhS[NC * 40];
  __shared__ f16_t WlS[NC * 40];
  __shared__ f16_t XS[64 * 40];
  int tid = threadIdx.x, lane = tid & 63, wid = tid >> 6;
  int lrow = lane & 15, lgrp = lane >> 4;
  int b = blockIdx.y, nBase = blockIdx.x * 64;
  const f16_t* __restrict__ Wth = p.wh[widx];
  const f16_t* __restrict__ Wtl = p.wl[widx];
  const float* bias = p.bia[widx];
  const f16_t* Xb = p.Xp + (size_t)b * LDK * 800;

  // X staging roles (threads < 128): k-pair x n-group
  int k2 = tid >> 3, ng = tid & 7;
  bool xact = tid < 128;
  bool nval = (nBase + ng * 8 + 7) < 800;

  uint4 rwh[SL], rwl[SL];
  half8 rx0, rx1;
  auto pfW = [&](int ks) {
#pragma unroll
    for (int s = 0; s < SL; ++s) {
      int slot = tid + s * 256;
      int row = slot >> 2, q = slot & 3;
      size_t g = (size_t)row * Kp + ks * 32 + q * 8;
      rwh[s] = *(const uint4*)(Wth + g);
      rwl[s] = *(const uint4*)(Wtl + g);
    }
  };
  auto pfX = [&](int ks) {
    if (!xact) return;
    int k = ks * 32 + 2 * k2;
    const f16_t* xs = Xb + (size_t)k * 800 + nBase + ng * 8;
    half8 zz = {};
    rx0 = (nval && k < K3) ? *(const half8*)xs : zz;
    rx1 = (nval && k + 1 < K3) ? *(const half8*)(xs + 800) : zz;
  };

  f32x4 aM[NMF][4], aC[NMF][4];
#pragma unroll
  for (int i = 0; i < NMF; ++i)
#pragma unroll
    for (int j = 0; j < 4; ++j) {
      aM[i][j] = (f32x4){0.f, 0.f, 0.f, 0.f};
      aC[i][j] = (f32x4){0.f, 0.f, 0.f, 0.f};
    }

  pfW(0);
  pfX(0);
  for (int ks = 0; ks < NKT; ++ks) {
    if (ks) __syncthreads();
#pragma unroll
    for (int s = 0; s < SL; ++s) {
      int slot = tid + s * 256;
      int row = slot >> 2, q = slot & 3;
      *(uint4*)(WhS + row * 40 + q * 8) = rwh[s];
      *(uint4*)(WlS + row * 40 + q * 8) = rwl[s];
    }
    if (xact) {
#pragma unroll
      for (int i = 0; i < 8; ++i) {
        union { f16_t h[2]; unsigned u; } pk;
        pk.h[0] = rx0[i];
        pk.h[1] = rx1[i];
        *(unsigned*)&XS[(ng * 8 + i) * 40 + 2 * k2] = pk.u;
      }
    }
    if (ks + 1 < NKT) { pfW(ks + 1); pfX(ks + 1); }
    __syncthreads();
    half8 fx[4];
#pragma unroll
    for (int nt = 0; nt < 4; ++nt) fx[nt] = *(const half8*)(XS + (nt * 16 + lrow) * 40 + lgrp * 8);
#pragma unroll
    for (int mf = 0; mf < NMF; ++mf) {
      int row = wid * MW + mf * 16 + lrow;
      half8 wh8 = *(const half8*)(WhS + row * 40 + lgrp * 8);
      half8 wl8 = *(const half8*)(WlS + row * 40 + lgrp * 8);
#pragma unroll
      for (int nt = 0; nt < 4; ++nt) {
        aM[mf][nt] = __builtin_amdgcn_mfma_f32_16x16x32_f16(wh8, fx[nt], aM[mf][nt], 0, 0, 0);
        aC[mf][nt] = __builtin_amdgcn_mfma_f32_16x16x32_f16(wl8, fx[nt], aC[mf][nt], 0, 0, 0);
      }
    }
  }

#pragma unroll
  for (int mf = 0; mf < NMF; ++mf)
#pragma unroll
    for (int nt = 0; nt < 4; ++nt) {
      int n = nBase + nt * 16 + lrow;
      if (n >= 800) continue;
#pragma unroll
      for (int j = 0; j < 4; ++j) {
        int co = wid * MW + mf * 16 + lgrp * 4 + j;
        float v = aM[mf][nt][j] + aC[mf][nt][j] * (1.0f / 2048.0f) + bias[co];
        if (MODE == 0) {
          if (co < 64) {
            p.U[(size_t)(b * 64 + co) * 800 + n] = sigm(v);
          } else {
            int jj = co - 64;
            float hv = hcur[(size_t)(b * 64 + jj) * 800 + n];
            float rhv = sigm(v) * hv;
            f16_t rh16 = (f16_t)rhv;
            p.Zrh[(size_t)(b * 64 + jj) * 800 + n] = rh16;                 // gconv#2 input
            p.Xp[((size_t)b * LDK + Pin + jj) * 800 + n] = rh16;           // cand-proj plane0 h-slot
          }
        } else {
          float u = p.U[(size_t)(b * 64 + co) * 800 + n];
          float hv = hcur[(size_t)(b * 64 + co) * 800 + n];
          hcur[(size_t)(b * 64 + co) * 800 + n] = (1.f - u) * hv + u * tanhf(v);
        }
      }
    }
}

// ================= memory attention =================

__global__ void __launch_bounds__(256) k_m1(Params p) {
  int gwid = (blockIdx.x * blockDim.x + threadIdx.x) >> 6;
  int nw = (gridDim.x * blockDim.x) >> 6;
  int lane = threadIdx.x & 63;
  for (int tile = gwid; tile < 1024; tile += nw) {
    int cx = tile & 15, b = tile >> 4;
    float acc[8] = {};
    const float* hrow = p.h1 + (size_t)b * 51200 + cx * 3200;
    const float* wbase = p.Wat + (size_t)cx * 3200 * 8;
    for (int i = lane; i < 3200; i += 64) {
      float hv = hrow[i];
      const float* wr = wbase + (size_t)i * 8;
#pragma unroll
      for (int j = 0; j < 8; ++j) acc[j] += hv * wr[j];
    }
#pragma unroll
    for (int s = 1; s < 64; s <<= 1) {
#pragma unroll
      for (int j = 0; j < 8; ++j) acc[j] += __shfl_xor(acc[j], s);
    }
    if (lane == 0) {
#pragma unroll
      for (int j = 0; j < 8; ++j) p.partial[((size_t)b * 16 + cx) * 8 + j] = acc[j];
    }
  }
}

__global__ void __launch_bounds__(256) k_m2(Params p, int t) {
  __shared__ float attv[512];
  int tid = threadIdx.x;
  if (tid < 64) {
    int b = tid;
    float q[8] = {};
    for (int cx = 0; cx < 16; ++cx)
#pragma unroll
      for (int j = 0; j < 8; ++j) q[j] += p.partial[((size_t)b * 16 + cx) * 8 + j];
    float sco[4], mx = -1e30f;
#pragma unroll
    for (int m = 0; m < 4; ++m) {
      float s = 0.f;
#pragma unroll
      for (int d = 0; d < 8; ++d) s += q[d] * p.mem[m * 8 + d];
      sco[m] = s;
      mx = fmaxf(mx, s);
    }
    float se = 0.f;
#pragma unroll
    for (int m = 0; m < 4; ++m) { sco[m] = expf(sco[m] - mx); se += sco[m]; }
#pragma unroll
    for (int d = 0; d < 8; ++d) {
      float av = 0.f;
#pragma unroll
      for (int m = 0; m < 4; ++m) av += (sco[m] / se) * p.mem[m * 8 + d];
      attv[b * 8 + d] = av;
    }
  }
  __syncthreads();
  int nt = gridDim.x * blockDim.x, id = blockIdx.x * blockDim.x + tid;
  for (int row = id; row < 51200; row += nt) {
    int b = row / 800, n = row - b * 800;
    const float* av = attv + b * 8;
    float attm[8];
#pragma unroll
    for (int d = 0; d < 8; ++d) {
      float s = 0.f;
#pragma unroll
      for (int m = 0; m < 8; ++m) s += av[m] * p.fc[(size_t)m * 6400 + n * 8 + d];
      attm[d] = s;
    }
    float o0 = p.projb[0], o1 = p.projb[1];
    const float* hb = p.h1 + (size_t)b * 51200 + n;
#pragma unroll 16
    for (int j = 0; j < 64; ++j) {
      float hv = hb[(size_t)j * 800];
      o0 += hv * p.projW[j * 2 + 0];
      o1 += hv * p.projW[j * 2 + 1];
    }
#pragma unroll
    for (int d = 0; d < 8; ++d) {
      o0 += attm[d] * p.projW[(64 + d) * 2 + 0];
      o1 += attm[d] * p.projW[(64 + d) * 2 + 1];
    }
    size_t base = ((size_t)(b * 12 + t) * 800 + n) * 2;
    p.dout[base + 0] = fmaxf(o0, 0.f);
    p.dout[base + 1] = fmaxf(o1, 0.f);
  }
}

// ================= host =================

extern "C" void kernel_launch(void* const* d_in, const int* in_sizes, int n_in,
                              void* d_out, int out_size, void* d_ws, size_t ws_size,
                              hipStream_t stream) {
  Params P;
  P.x_seq = (const float*)d_in[0];
  P.t_x = (const float*)d_in[1];
  P.t_y = (const float*)d_in[2];
  P.G = (const float*)d_in[3];
  P.Wraw[0] = (const float*)d_in[4];  P.bia[0] = (const float*)d_in[5];
  P.Wraw[1] = (const float*)d_in[6];  P.bia[1] = (const float*)d_in[7];
  P.Wraw[2] = (const float*)d_in[8];  P.bia[2] = (const float*)d_in[9];
  P.Wraw[3] = (const float*)d_in[10]; P.bia[3] = (const float*)d_in[11];
  P.Wraw[4] = (const float*)d_in[12]; P.bia[4] = (const float*)d_in[13];
  P.Wraw[5] = (const float*)d_in[14]; P.bia[5] = (const float*)d_in[15];
  P.Wraw[6] = (const float*)d_in[16]; P.bia[6] = (const float*)d_in[17];
  P.Wraw[7] = (const float*)d_in[18]; P.bia[7] = (const float*)d_in[19];
  P.mW1 = (const float*)d_in[20];
  P.mb1 = (const float*)d_in[21];
  P.mW2 = (const float*)d_in[22];
  P.mb2 = (const float*)d_in[23];
  P.mem = (const float*)d_in[24];
  P.Wa = (const float*)d_in[25];
  P.fc = (const float*)d_in[26];
  P.projW = (const float*)d_in[27];
  P.projb = (const float*)d_in[28];
  P.dout = (float*)d_out;

  float* ws = (float*)d_ws;
  size_t off = 0;
  auto alloc = [&](size_t nel) { float* q = ws + off; off += (nel + 3) & ~(size_t)3; return q; };
  P.T2h = (f16_t*)alloc(320000);
  P.Atp = (f16_t*)alloc((size_t)25 * NMP * 32 / 2);
  P.Zin = (f16_t*)alloc((size_t)8192 * 800 / 2);
  P.Zrh = (f16_t*)alloc((size_t)4096 * 800 / 2);
  P.Xp = (f16_t*)alloc((size_t)64 * LDK * 800 / 2);
  P.U = alloc((size_t)4096 * 800);
  P.h0 = alloc((size_t)4096 * 800);
  P.h1 = alloc((size_t)4096 * 800);
  P.txe = alloc((size_t)768 * 1600);
  P.tye = alloc((size_t)768 * 1600);
  P.hidb = alloc(15360);
  P.partial = alloc(8192);
  P.Wat = alloc(409600);
  const int kpnc[8] = {224 * 128, 224 * 64, 384 * 128, 384 * 64, 224 * 128, 224 * 64, 384 * 128, 384 * 64};
  for (int w = 0; w < 8; ++w) {
    P.wh[w] = (f16_t*)alloc((kpnc[w] + 1) / 2);
    P.wl[w] = (f16_t*)alloc((kpnc[w] + 1) / 2);
  }

  k_pre0<<<512, 256, 0, stream>>>(P);
  k_pre1<<<512, 256, 0, stream>>>(P);
  k_pre2<<<512, 256, 0, stream>>>(P);

  auto cell = [&](int dec, int t) {
    // ---- layer 0 ----
    g_pack0<<<4352, 256, 0, stream>>>(P, dec, t);
    g_gconv<68><<<dim3(13, 34), 256, 0, stream>>>(P, P.Zin, 68, 0);
    g_proj<128, 0><<<dim3(13, 64), 256, 0, stream>>>(P, dec * 4 + 0, 204, 4, P.h0);
    g_gconv<64><<<dim3(13, 32), 256, 0, stream>>>(P, P.Zrh, 68, 4);
    g_proj<64, 1><<<dim3(13, 64), 256, 0, stream>>>(P, dec * 4 + 1, 204, 4, P.h0);
    // ---- layer 1 ----
    g_pack1<<<8192, 256, 0, stream>>>(P);
    g_gconv<128><<<dim3(13, 64), 256, 0, stream>>>(P, P.Zin, 128, 0);
    g_proj<128, 0><<<dim3(13, 64), 256, 0, stream>>>(P, dec * 4 + 2, 384, 64, P.h1);
    g_gconv<64><<<dim3(13, 32), 256, 0, stream>>>(P, P.Zrh, 128, 64);
    g_proj<64, 1><<<dim3(13, 64), 256, 0, stream>>>(P, dec * 4 + 3, 384, 64, P.h1);
  };

  for (int t = 0; t < 12; ++t) cell(0, t);
  for (int t = 0; t < 12; ++t) {
    cell(1, t);
    k_m1<<<256, 256, 0, stream>>>(P);
    k_m2<<<200, 256, 0, stream>>>(P, t);
  }
}